// Round 9
// baseline (283.217 us; speedup 1.0000x reference)
//
#include <hip/hip_runtime.h>
#include <stdint.h>

// Problem constants
#define N_POINTS   34100
#define BATCH      8
#define N_GT       200
#define NLEV       5
#define NCAND      3500
#define MAX_DET    300
#define SCORE_TH   0.05f
#define NMS_TH     0.5f
#define IMG        1280.0f
#define NBIN       4096
// Exact threshold: RN(inter/denom) > 0.5  <=>  inter > T, T=(0.5+2^-25)*denom
// f32 fast path + f64 boundary fallback (R11-verified, absmax 0).
#define MTH 0.50000002980232238769531250

// Output layout (float32 flat, reference return order)
#define OUT_MATCH  0        // 8*34100
#define OUT_BOXES  272800   // 8*300*4
#define OUT_SCORES 282400   // 8*300
#define OUT_LABELS 284800   // 8*300
#define OUT_VALID  287200   // 8*300

// Workspace layout (bytes)
#define WS_KEYS    0              // u32[8*34100]   = 1,091,200
// R21: candidate/tie buffers in the keys->sbox gap (1,091,200..2,632,192)
#define WS_CAND    1091200        // u64[8][4096]   =   262,144
#define WS_TIEB    1353344        // u64[8][2048]   =   131,072
#define WS_CNT     1484416        // u32[16] (cnt[8], tcnt[8]) = 64
#define CAND_CAP   4096
#define TIEB_CAP   2048
#define WS_SBOX    2632192        // float4[8*3500] =   448,000
#define WS_SSC     3080192        // float[8*3500]  =   112,000
#define WS_MASK    3192192        // u64[8*98560]   = 6,307,840
#define WS_DIAG    9500032        // u64[8*3520]    =   225,280
// R15: per-chunk partial level-histograms, ALIASED onto head of WS_MASK
// (stream-ordered liveness: consumed before mask_kernel rewrites).
#define WS_HIST    WS_MASK        // u32[8][5][8][4096] = 5,242,880
#define HSUB       8
#define MASK_STRIDE 98560
#define DIAG_STRIDE 3520

// R16: XCD-local batch chains (batch = blockIdx%8) — kept.
// R17/R19/R20: in-kernel L2 warming — kept for scan.
// R18: coalesced ghist->swizzled-LDS select — kept.
// R20 split localized the 51us dark cost to C/D/E at 8-block parallelism.
// R21: C parallelized to 64 blocks (order-independence: E's counting sort +
// exact intra-digit rank and D's key-comparison rank are insensitive to sk
// input order) appending to GLOBAL per-batch buffers via wave-aggregated
// device atomics (~10K total; R14's 273K was the problem, not the mechanism).
// sort_kernel (8 blocks) does only D/E/decode on <=3500 elements.

typedef unsigned long long u64;
typedef uint32_t u32;

// Packed upper-triangle row offset: row c stores words (c>>6)..54
__device__ __forceinline__ int mask_off(int c) {
    int g = c >> 6;
    return 64 * (55 * g - (g * (g - 1)) / 2) + (c - (g << 6)) * (55 - g);
}

__device__ __forceinline__ int level_of(int p) {
    return (p < 25600) ? 0 : (p < 32000) ? 1 : (p < 33600) ? 2 : (p < 34000) ? 3 : 4;
}
__device__ __forceinline__ int loff_of(int l) {
    return (l == 0) ? 0 : (l == 1) ? 25600 : (l == 2) ? 32000 : (l == 3) ? 33600 : 34000;
}
__device__ __forceinline__ int k_of(int l) {
    return (l == 0) ? 1000 : (l == 1) ? 1000 : (l == 2) ? 1000 : (l == 3) ? 400 : 100;
}
__device__ __forceinline__ u64 readlane64(u64 v, int t) {
    u32 lo = (u32)__builtin_amdgcn_readlane((int)(u32)v, t);
    u32 hi = (u32)__builtin_amdgcn_readlane((int)(u32)(v >> 32), t);
    return ((u64)hi << 32) | lo;
}

// ---------------------------------------------------------------------------
// Kernel 1 (R20): fused match + hist. Grid 240: g = bid>>3, batch = bid&7.
// ---------------------------------------------------------------------------
__global__ __launch_bounds__(1024)
void match_hist_kernel(const float* __restrict__ points,
                       const float* __restrict__ gt,
                       const float* __restrict__ logits,
                       float* __restrict__ out_match,
                       u32* __restrict__ keys,
                       u32* __restrict__ ghist) {
#pragma clang fp contract(off)
    __shared__ float bx1[N_GT], by1[N_GT], bx2[N_GT], by2[N_GT], ar[N_GT];
    __shared__ u32 hh[NBIN];
    const int b = blockIdx.x & 7;
    const int g = blockIdx.x >> 3;           // 0..29
    const int tid = threadIdx.x;

    if (g < 17) {
        // ---- match part: points [g*2048, g*2048+2048) ----
        const int base = g * 2048 + tid;
        for (int j = tid; j < N_GT; j += 1024) {
            float x1 = gt[(b * N_GT + j) * 4 + 0];
            float y1 = gt[(b * N_GT + j) * 4 + 1];
            float x2 = gt[(b * N_GT + j) * 4 + 2];
            float y2 = gt[(b * N_GT + j) * 4 + 3];
            bx1[j] = x1; by1[j] = y1; bx2[j] = x2; by2[j] = y2;
            ar[j] = (x2 - x1) * (y2 - y1);
        }
        __syncthreads();

        const float BIGF = 2147483648.0f;   // float32(2^31-1) rounds to 2^31
        float px[2], py[2], best[2];
        int bi[2];
#pragma unroll
        for (int k = 0; k < 2; ++k) {
            int p = base + k * 1024;
            int pc = (p < N_POINTS) ? p : 0;
            px[k] = points[pc * 2 + 0];
            py[k] = points[pc * 2 + 1];
            best[k] = BIGF; bi[k] = -1;
        }
        for (int j = 0; j < N_GT; ++j) {
            float x1 = bx1[j], y1 = by1[j], x2 = bx2[j], y2 = by2[j], a = ar[j];
#pragma unroll
            for (int k = 0; k < 2; ++k) {
                bool inside = (px[k] >= x1) && (px[k] <= x2) &&
                              (py[k] >= y1) && (py[k] <= y2);
                float cost = inside ? a : BIGF;
                if (cost < best[k]) { best[k] = cost; bi[k] = j; }   // strict <
            }
        }
#pragma unroll
        for (int k = 0; k < 2; ++k) {
            int p = base + k * 1024;
            if (p >= N_POINTS) continue;
            out_match[b * N_POINTS + p] = (float)bi[k];
        }
    } else {
        // ---- hist part: sigmoid keys + partial level histogram ----
        const int f = g - 17;                // 0..12
        int lev, sub, p0, cnt;
        if (f < 8)       { lev = 0; sub = f;     p0 = f * 3200;               cnt = 3200; }
        else if (f < 10) { lev = 1; sub = f - 8; p0 = 25600 + (f - 8) * 3200; cnt = 3200; }
        else if (f == 10){ lev = 2; sub = 0;     p0 = 32000;                  cnt = 1600; }
        else if (f == 11){ lev = 3; sub = 0;     p0 = 33600;                  cnt = 400;  }
        else             { lev = 4; sub = 0;     p0 = 34000;                  cnt = 100;  }

        for (int i = tid; i < NBIN; i += 1024) hh[i] = 0u;
        __syncthreads();

        for (int i = tid; i < cnt; i += 1024) {
            int p = p0 + i;
            float lg = logits[b * N_POINTS + p];
            float s = 1.0f / (1.0f + expf(-lg));
            u32 u = __float_as_uint(s);
            u32 key = (u & 0x80000000u) ? ~u : (u | 0x80000000u);
            keys[b * N_POINTS + p] = key;
            atomicAdd(&hh[(key >> 19) & 4095u], 1u);
        }
        __syncthreads();

        u32* outp = ghist + (((u32)b * NLEV + (u32)lev) * HSUB + (u32)sub) * NBIN;
        for (int i = tid; i < NBIN; i += 1024) outp[i] = hh[i];
    }
}

// sel storage: unused ghist sub-slot [lev4][sub7].
#define SEL_OFF(b) ((((u32)(b) * NLEV + 4) * HSUB + 7) * NBIN)

// ---------------------------------------------------------------------------
// Kernel 2a: select — A' coalesced ghist sum -> swizzled LDS + B's 5 parallel
// threshold selects. Writes sTl/skkl (10 u32/batch) to sel slot.
// ---------------------------------------------------------------------------
#define LSWZ(j) (((j) & 63) * 65 + ((j) >> 6))
__global__ __launch_bounds__(1024)
void select_kernel(u32* __restrict__ ghist) {
    __shared__ u32 lsb[5 * 4160];            // 83,200B
    __shared__ u32 sTl[NLEV], skkl[NLEV];
    const int b = blockIdx.x;
    const int tid = threadIdx.x;
    const int lane = tid & 63;
    const int wid = tid >> 6;

    {
        const u32* hb = ghist + (u32)b * (NLEV * HSUB * NBIN);
#pragma unroll
        for (int lev = 0; lev < NLEV; ++lev) {
            const int SUBS = (lev == 0) ? 8 : (lev == 1) ? 2 : 1;
            const u32* hl = hb + lev * HSUB * NBIN + tid;
            u32 s0 = 0, s1 = 0, s2 = 0, s3 = 0;
#pragma unroll
            for (int sub = 0; sub < SUBS; ++sub) {
                const u32* hs = hl + sub * NBIN;
                s0 += hs[0]; s1 += hs[1024]; s2 += hs[2048]; s3 += hs[3072];
            }
            u32* lv = lsb + lev * 4160;
            lv[LSWZ(tid)]        = s0;
            lv[LSWZ(tid + 1024)] = s1;
            lv[LSWZ(tid + 2048)] = s2;
            lv[LSWZ(tid + 3072)] = s3;
        }
    }
    __syncthreads();

    if (wid < NLEV) {
        const u32 K = (u32)k_of(wid);
        const u32* hh = lsb + wid * 4160;
        u32 S = 0;
#pragma unroll 16
        for (int i = 0; i < 64; ++i) S += hh[i * 65 + lane];   // bins lane*64+i
        u32 acc = S;
#pragma unroll
        for (int off = 1; off < 64; off <<= 1) {
            u32 v = (u32)__shfl_down((int)acc, off);
            if (lane + off < 64) acc += v;
        }
        u32 sfxAfter = acc - S;
        bool hit = (sfxAfter < K) && (sfxAfter + S >= K);
        u64 bal = __ballot(hit);
        int Lg = (int)__builtin_ctzll(bal);
        u32 sfxG = (u32)__shfl((int)sfxAfter, Lg);

        u32 v = hh[lane * 65 + Lg];          // bin Lg*64+lane
        u32 acc2 = v;
#pragma unroll
        for (int off = 1; off < 64; off <<= 1) {
            u32 t = (u32)__shfl_down((int)acc2, off);
            if (lane + off < 64) acc2 += t;
        }
        u32 sfx2 = sfxG + acc2 - v;
        bool hit2 = (sfx2 < K) && (sfx2 + v >= K);
        if (hit2) { sTl[wid] = (u32)(Lg * 64 + lane); skkl[wid] = K - sfx2; }
    }
    __syncthreads();
    if (tid < NLEV) {
        u32* selp = ghist + SEL_OFF(b);
        selp[tid] = sTl[tid];
        selp[NLEV + tid] = skkl[tid];
    }
}

// ---------------------------------------------------------------------------
// Kernel 2b (R21): compact — 64 blocks (slice = bid>>3, batch = bid&7).
// Each block classifies its 4263-point slice; defs/ties appended to global
// per-batch buffers via wave-aggregated device atomics. Order-free.
// ---------------------------------------------------------------------------
#define SLICE_PTS 4263
__global__ __launch_bounds__(1024)
void compact_kernel(const u32* __restrict__ keys,
                    const u32* __restrict__ ghist,
                    u64* __restrict__ cand,
                    u64* __restrict__ tieb,
                    u32* __restrict__ cnts) {
    __shared__ u32 sTl[NLEV];
    const int b = blockIdx.x & 7;
    const int sl = blockIdx.x >> 3;          // 0..7
    const int tid = threadIdx.x;
    const int lane = tid & 63;
    if (tid < NLEV) sTl[tid] = ghist[SEL_OFF(b) + tid];
    __syncthreads();

    const u32* kk_ = keys + b * N_POINTS;
    u64* cb = cand + b * CAND_CAP;
    u64* tbg = tieb + b * TIEB_CAP;
    u32* cnt = cnts + b;
    u32* tcnt = cnts + 8 + b;
    const int p0 = sl * SLICE_PTS;
    const int p1 = (p0 + SLICE_PTS < N_POINTS) ? (p0 + SLICE_PTS) : N_POINTS;
    const u64 below = (lane == 0) ? 0ull : (~0ull >> (64 - lane));

    const int CH = 4 * 1024;
    for (int it = p0; it < p1; it += CH) {
        u32 key4[4]; int pc4[4]; bool act4[4];
#pragma unroll
        for (int u = 0; u < 4; ++u) {
            int i = it + u * 1024 + tid;
            act4[u] = (i < p1);
            pc4[u] = act4[u] ? i : (N_POINTS - 1);
            key4[u] = kk_[pc4[u]];
        }
#pragma unroll
        for (int u = 0; u < 4; ++u) {
            bool active = act4[u];
            int pc = pc4[u];
            u32 key = key4[u];
            int l = level_of(pc);
            u32 digit = (key >> 19) & 4095u;
            u32 T = sTl[l];
            bool isDef = active && (digit > T);
            bool isTie = active && (digit == T);
            u64 k50 = ((u64)key << 18) | ((u64)(7 - l) << 15)
                    | (u64)(32767 - (pc - loff_of(l)));
            u64 grp = __ballot(isDef);
            if (grp) {
                int leader = (int)__builtin_ctzll(grp);
                u32 base_ = 0;
                if (lane == leader)
                    base_ = atomicAdd(cnt, (u32)__builtin_popcountll(grp));
                base_ = (u32)__shfl((int)base_, leader);
                if (isDef) cb[base_ + (u32)__builtin_popcountll(grp & below)] = k50;
            }
            u64 tg = __ballot(isTie);
            if (tg) {
                int leader = (int)__builtin_ctzll(tg);
                u32 base_ = 0;
                if (lane == leader)
                    base_ = atomicAdd(tcnt, (u32)__builtin_popcountll(tg));
                base_ = (u32)__shfl((int)base_, leader);
                if (isTie) {
                    u32 pos = base_ + (u32)__builtin_popcountll(tg & below);
                    if (pos < TIEB_CAP) tbg[pos] = k50;
                }
            }
        }
    }
}

// ---------------------------------------------------------------------------
// Kernel 2c (R21): sort — load cands+ties to LDS, D tie-select, E counting
// sort + exact rank, decode. Only ~3500 elements of serial-ish work.
// ---------------------------------------------------------------------------
#define SORT_T 1024
__global__ __launch_bounds__(SORT_T)
void sort_kernel(const u64* __restrict__ cand,
                 const u64* __restrict__ tieb,
                 const u32* __restrict__ cnts,
                 const u32* __restrict__ ghist,
                 const float* __restrict__ reg,
                 const float* __restrict__ points,
                 float* __restrict__ sboxes,
                 float* __restrict__ sscores) {
#pragma clang fp contract(off)
    __shared__ __align__(16) char smem[131072];
    u64* sk   = (u64*)smem;                  //     0..32768 : 4096 u64
    u64* tb   = (u64*)(smem + 32768);        // 32768..65536 : 4096 u64 (D)
    u64* aux  = (u64*)(smem + 65536);        // 65536..98304 : 4096 u64 (E)
    u32* h    = (u32*)(smem + 98304);        // 98304..114688: 4096 u32 (E)
    u32* bs   = (u32*)(smem + 114688);       // 114688..131072: 4096 u32 (E)
    __shared__ u32 skkl[NLEV], wt[16];
    __shared__ u32 scnt;

    const int b = blockIdx.x;
    const int tid = threadIdx.x;
    const int lane = tid & 63;
    const int wid = tid >> 6;

    const int n = (int)cnts[b];              // defs (<= 3500)
    int t = (int)cnts[8 + b];                // ties
    if (t > TIEB_CAP) t = TIEB_CAP;
    if (tid == 0) scnt = (u32)n;
    if (tid < NLEV) skkl[tid] = ghist[SEL_OFF(b) + NLEV + tid];

    // load candidates + ties into LDS (coalesced)
    for (int i = tid; i < n; i += SORT_T) sk[i] = cand[b * CAND_CAP + i];
    for (int i = tid; i < t; i += SORT_T) tb[i] = tieb[b * TIEB_CAP + i];
    __syncthreads();

    // ---- Phase D: tie-select (rank among same-level ties), append to sk ----
    const u64 below = (lane == 0) ? 0ull : (~0ull >> (64 - lane));
    for (int j0 = tid; j0 - tid < t; j0 += SORT_T) {
        bool active = j0 < t;
        u64 kj = active ? tb[j0] : 0ull;
        u32 lvtag = (u32)(kj >> 15) & 7u;
        int r = 0;
        for (int i = 0; i < t; ++i) {
            u64 ki = tb[i];                   // broadcast read
            r += (ki > kj && (((u32)(ki >> 15) & 7u) == lvtag)) ? 1 : 0;
        }
        bool inc = active && (r < (int)skkl[7 - lvtag]);
        u64 grp = __ballot(inc);
        if (grp) {
            int leader = (int)__builtin_ctzll(grp);
            u32 base_ = 0;
            if (lane == leader)
                base_ = atomicAdd(&scnt, (u32)__builtin_popcountll(grp));
            base_ = (u32)__shfl((int)base_, leader);
            if (inc) sk[base_ + (u32)__builtin_popcountll(grp & below)] = kj;
        }
    }
    __syncthreads();
    const int total = (int)scnt;             // == 3500 by construction

    // ---- Phase E: counting sort by digit (desc) + exact intra-digit rank ----
    for (int i = tid; i < NBIN; i += SORT_T) h[i] = 0u;
    __syncthreads();
    for (int i = tid; i < total; i += SORT_T)
        atomicAdd(&h[(u32)(sk[i] >> 37) & 4095u], 1u);
    __syncthreads();

    u32 t0 = h[4095 - 4 * tid];
    u32 t1 = h[4095 - (4 * tid + 1)];
    u32 t2 = h[4095 - (4 * tid + 2)];
    u32 t3 = h[4095 - (4 * tid + 3)];
    u32 tsum = t0 + t1 + t2 + t3;
    u32 sc_ = tsum;
#pragma unroll
    for (int off = 1; off < 64; off <<= 1) {
        u32 v = (u32)__shfl_up((int)sc_, off);
        if (lane >= off) sc_ += v;
    }
    if (lane == 63) wt[wid] = sc_;
    __syncthreads();
    if (tid < 64) {
        u32 v = (tid < 16) ? wt[tid] : 0u;
        u32 s2 = v;
#pragma unroll
        for (int off = 1; off < 16; off <<= 1) {
            u32 x = (u32)__shfl_up((int)s2, off);
            if (tid >= off) s2 += x;
        }
        if (tid < 16) wt[tid] = s2 - v;      // exclusive wave offsets
    }
    __syncthreads();
    u32 run = (sc_ - tsum) + wt[wid];
    bs[4095 - 4 * tid] = run;       run += t0;
    bs[4095 - (4 * tid + 1)] = run; run += t1;
    bs[4095 - (4 * tid + 2)] = run; run += t2;
    bs[4095 - (4 * tid + 3)] = run;
    __syncthreads();
    for (int i = tid; i < NBIN; i += SORT_T) h[i] = 0u;
    __syncthreads();
    for (int i = tid; i < total; i += SORT_T) {
        u64 k = sk[i];
        u32 d = (u32)(k >> 37) & 4095u;
        u32 pos = bs[d] + atomicAdd(&h[d], 1u);
        aux[pos] = k;
    }
    __syncthreads();
    for (int p = tid; p < total; p += SORT_T) {
        u64 kp = aux[p];
        u32 d = (u32)(kp >> 37) & 4095u;
        u32 gbase = bs[d];
        u32 gend = (d == 0) ? (u32)total : bs[d - 1];
        u32 r = 0;
        for (u32 q = gbase; q < gend; ++q) r += (aux[q] > kp) ? 1u : 0u;
        sk[gbase + r] = kp;                  // unique keys -> exact slot
    }
    __syncthreads();

    // decode + write sorted candidates
    for (int r = tid; r < NCAND; r += SORT_T) {
        float x1 = 0.f, y1 = 0.f, x2 = 0.f, y2 = 0.f, sc = 0.f;
        if (r < total) {
            u64 k50 = sk[r];
            int lowb = (int)(k50 & 0x3FFFFull);
            int l = 7 - (lowb >> 15);
            int idxl = 32767 - (lowb & 32767);
            int p = loff_of(l) + idxl;
            u32 key32 = (u32)(k50 >> 18);
            sc = __uint_as_float(key32 ^ 0x80000000u);
            int gp = b * N_POINTS + p;
            float l_ = reg[gp * 4 + 0] * IMG;
            float t_ = reg[gp * 4 + 1] * IMG;
            float r_ = reg[gp * 4 + 2] * IMG;
            float bb = reg[gp * 4 + 3] * IMG;
            float px = points[p * 2 + 0];
            float py = points[p * 2 + 1];
            x1 = fminf(fmaxf(px - l_, 0.0f), IMG);
            y1 = fminf(fmaxf(py - t_, 0.0f), IMG);
            x2 = fminf(fmaxf(px + r_, 0.0f), IMG);
            y2 = fminf(fmaxf(py + bb, 0.0f), IMG);
        }
        int slot = b * NCAND + r;
        sboxes[slot * 4 + 0] = x1;
        sboxes[slot * 4 + 1] = y1;
        sboxes[slot * 4 + 2] = x2;
        sboxes[slot * 4 + 3] = y2;
        sscores[slot] = sc;
    }
}

// ---------------------------------------------------------------------------
// Kernel 3: suppression-mask matrix (R13 load-balanced mirror pairs).
// R16: 1D grid of 880, batch = bid&7.
// ---------------------------------------------------------------------------
__global__ __launch_bounds__(256)
void mask_kernel(const float* __restrict__ sboxes,
                 const float* __restrict__ sscores,
                 u64* __restrict__ mask,
                 u64* __restrict__ diag) {
#pragma clang fp contract(off)
    const int b = blockIdx.x & 7;                // XCD-local batch
    const int gx = blockIdx.x >> 3;              // 0..109
    const int wv = threadIdx.x >> 6;
    const int lane = threadIdx.x & 63;
    const int NG = (NCAND + 3) >> 2;             // 875 row-groups
    const int NH = (NG + 1) >> 1;                // 438 balanced pairs
    const int gidx = gx * 4 + wv;
    if (gidx >= NH) return;

    const float4* gb = (const float4*)sboxes + b * NCAND;
    const float* gs = sscores + b * NCAND;
    u64* mout = mask + (size_t)b * MASK_STRIDE;
    u64* dout = diag + (size_t)b * DIAG_STRIDE;

    for (int s = 0; s < 2; ++s) {
        const int g0 = (s == 0) ? gidx : (NG - 1 - gidx);
        if (s == 1 && g0 == gidx) break;         // odd middle processed once
        const int c0 = g0 << 2;

        float4 bc[4]; float a1[4]; bool ok[4]; int g[4]; u64* rp[4];
        bool any = false;
#pragma unroll
        for (int i = 0; i < 4; ++i) {
            int c = c0 + i;
            int cc = (c < NCAND) ? c : (NCAND - 1);
            bc[i] = gb[cc];
            a1[i] = (bc[i].z - bc[i].x) * (bc[i].w - bc[i].y);
            ok[i] = (c < NCAND) && (gs[cc] > SCORE_TH);
            g[i] = cc >> 6;
            rp[i] = mout + mask_off(cc) - g[i];
            any |= ok[i];
        }
        if (!any) continue;                      // wave-uniform

        for (int w = (c0 >> 6); w < 55; ++w) {
            int cj = (w << 6) + lane;
            float4 bj = (cj < NCAND) ? gb[cj] : make_float4(0.f, 0.f, 0.f, 0.f);
            float a2 = (bj.z - bj.x) * (bj.w - bj.y);
#pragma unroll
            for (int i = 0; i < 4; ++i) {
                float x1 = fmaxf(bc[i].x, bj.x);
                float y1 = fmaxf(bc[i].y, bj.y);
                float x2 = fminf(bc[i].z, bj.z);
                float y2 = fminf(bc[i].w, bj.w);
                float inter = fmaxf(x2 - x1, 0.f) * fmaxf(y2 - y1, 0.f);
                float denom = a1[i] + a2 - inter + 1e-9f;   // ref association
                float hf = 0.5f * denom;                    // exact
                float rr = fmaf(0x1p-25f, denom, hf);       // RN(T)
                u64 bits = __ballot(inter > rr);
                u64 eq = __ballot(inter == rr);
                if (eq) {                                   // boundary: exact f64
                    u64 fb = __ballot((double)inter > MTH * (double)denom);
                    bits |= (eq & fb);
                }
                if (lane == 0 && ok[i] && w >= g[i]) {
                    rp[i][w] = bits;
                    if (w == g[i]) dout[c0 + i] = bits;     // dense diagonal
                }
            }
        }
    }
}

// ---------------------------------------------------------------------------
// Kernel 4: sorted-order NMS scan (R20 form: 8-deep warm MLP + sboxes/
// sscores warm; store-free pick loop with LDS pick list).
// ---------------------------------------------------------------------------
__global__ __launch_bounds__(1024)
void scan_kernel(const float* __restrict__ sboxes,
                 const float* __restrict__ sscores,
                 const u64* __restrict__ mask,
                 const u64* __restrict__ diag,
                 float* __restrict__ out) {
    __shared__ u32 pick_idx[MAX_DET];
    const int b = blockIdx.x;
    const int tid = threadIdx.x;
    const u64* mrow = mask + (size_t)b * MASK_STRIDE;
    const u64* drow = diag + (size_t)b * DIAG_STRIDE;
    const float4* gb = (const float4*)sboxes + b * NCAND;
    const float* gs = sscores + b * NCAND;

    if (tid >= 64) {
        // ---- L2-warming waves: mask (8-deep) + diag + sboxes + sscores ----
        const uint4* mp = (const uint4*)mrow;          // 49280 uint4
        const uint4* dp = (const uint4*)drow;          // 1760 uint4
        const uint4* bp = (const uint4*)gb;            // 3500 uint4
        const uint4* sp = (const uint4*)gs;            // 875 uint4
        const int t = tid - 64;                        // 0..959
        u32 a0 = 0, a1 = 0, a2 = 0, a3 = 0, a4 = 0, a5 = 0, a6 = 0, a7 = 0;
        int i = t;
        for (; i + 6720 < 49280; i += 7680) {          // 8 loads in flight
            uint4 v0 = mp[i];
            uint4 v1 = mp[i + 960];
            uint4 v2 = mp[i + 1920];
            uint4 v3 = mp[i + 2880];
            uint4 v4 = mp[i + 3840];
            uint4 v5 = mp[i + 4800];
            uint4 v6 = mp[i + 5760];
            uint4 v7 = mp[i + 6720];
            a0 ^= v0.x ^ v0.y ^ v0.z ^ v0.w;
            a1 ^= v1.x ^ v1.y ^ v1.z ^ v1.w;
            a2 ^= v2.x ^ v2.y ^ v2.z ^ v2.w;
            a3 ^= v3.x ^ v3.y ^ v3.z ^ v3.w;
            a4 ^= v4.x ^ v4.y ^ v4.z ^ v4.w;
            a5 ^= v5.x ^ v5.y ^ v5.z ^ v5.w;
            a6 ^= v6.x ^ v6.y ^ v6.z ^ v6.w;
            a7 ^= v7.x ^ v7.y ^ v7.z ^ v7.w;
        }
        for (; i < 49280; i += 960) {
            uint4 v = mp[i];
            a0 ^= v.x ^ v.y ^ v.z ^ v.w;
        }
        if (t < 880) {                                 // diag: 2 per thread
            uint4 v0 = dp[t];
            uint4 v1 = dp[t + 880];
            a1 ^= v0.x ^ v0.y ^ v0.z ^ v0.w;
            a2 ^= v1.x ^ v1.y ^ v1.z ^ v1.w;
        }
        for (int j = t; j < 3500; j += 960) {          // sboxes
            uint4 v = bp[j];
            a3 ^= v.x ^ v.y ^ v.z ^ v.w;
        }
        if (t < 875) {                                 // sscores
            uint4 v = sp[t];
            a4 ^= v.x ^ v.y ^ v.z ^ v.w;
        }
        u32 acc = (a0 ^ a1) ^ (a2 ^ a3) ^ (a4 ^ a5) ^ (a6 ^ a7);
        asm volatile("" :: "v"(acc));                  // keep loads live
        return;
    }

    const int lane = tid;                    // 64 threads = 1 wave

    float* ob = out + OUT_BOXES  + b * MAX_DET * 4;
    float* os = out + OUT_SCORES + b * MAX_DET;
    float* ol = out + OUT_LABELS + b * MAX_DET;
    float* ov = out + OUT_VALID  + b * MAX_DET;

    u64 m = 0ull;                            // lane f owns future-word f
    u64 rowN = drow[lane];                   // contiguous diagonal prefetch
    float sjN = gs[lane];

    int kept = 0;
    for (int w = 0; w < 55; ++w) {
        const int wbase = w << 6;
        const u64 row = rowN;
        const float sj = sjN;
        if (w < 54) {                        // prefetch next word (contiguous)
            int cn = wbase + 64 + lane;
            int cc = (cn < NCAND) ? cn : (NCAND - 1);
            rowN = drow[cc];
            float s = gs[cc];
            sjN = (cn < NCAND) ? s : 0.f;
        }
        int c = wbase + lane;
        u64 bad = __ballot(!((c < NCAND) && (sj > SCORE_TH)));
        u64 cur = readlane64(m, w) | bad;
        u64 km = 0ull;
        while (kept < MAX_DET) {
            u64 avail = ~cur;
            if (avail == 0ull) break;
            int t = (int)__builtin_ctzll(avail);       // uniform
            u64 r = readlane64(row, t);                // keep t's intra bits
            cur |= r | (1ull << t);
            km |= 1ull << t;
            if (lane == 0) pick_idx[kept] = (u32)(wbase + t);  // LDS, off vmem path
            kept++;
        }
        if (km) {
            const bool lr = (lane >= w && lane < 55);
            const int lo = lane - w;
            u64 acc = 0ull;
            while (km) {
#define POPBIT(tn) int tn = -1; if (km) { tn = (int)__builtin_ctzll(km); km &= km - 1ull; }
                POPBIT(t0) POPBIT(t1) POPBIT(t2) POPBIT(t3)
                POPBIT(t4) POPBIT(t5) POPBIT(t6) POPBIT(t7)
#undef POPBIT
                u64 v0 = 0, v1 = 0, v2 = 0, v3 = 0, v4 = 0, v5 = 0, v6 = 0, v7 = 0;
                if (lr) {
                    v0 = mrow[mask_off(wbase + t0) + lo];
                    if (t1 >= 0) v1 = mrow[mask_off(wbase + t1) + lo];
                    if (t2 >= 0) v2 = mrow[mask_off(wbase + t2) + lo];
                    if (t3 >= 0) v3 = mrow[mask_off(wbase + t3) + lo];
                    if (t4 >= 0) v4 = mrow[mask_off(wbase + t4) + lo];
                    if (t5 >= 0) v5 = mrow[mask_off(wbase + t5) + lo];
                    if (t6 >= 0) v6 = mrow[mask_off(wbase + t6) + lo];
                    if (t7 >= 0) v7 = mrow[mask_off(wbase + t7) + lo];
                }
                acc |= ((v0 | v1) | (v2 | v3)) | ((v4 | v5) | (v6 | v7));
            }
            m |= acc;
        }
        if (kept >= MAX_DET) break;
    }

    // ---- coalesced epilogue: gather picked candidates, write outputs ----
    for (int k = lane; k < kept; k += 64) {
        u32 c = pick_idx[k];                 // same-wave LDS, no barrier needed
        float4 bx = gb[c];
        float s = gs[c];
        ob[k * 4 + 0] = bx.x;
        ob[k * 4 + 1] = bx.y;
        ob[k * 4 + 2] = bx.z;
        ob[k * 4 + 3] = bx.w;
        os[k] = s;
        ol[k] = 0.0f;
        ov[k] = 1.0f;
    }
    for (int k = kept + lane; k < MAX_DET; k += 64) {
        ob[k * 4 + 0] = 0.f; ob[k * 4 + 1] = 0.f;
        ob[k * 4 + 2] = 0.f; ob[k * 4 + 3] = 0.f;
        os[k] = 0.f; ol[k] = -1.f; ov[k] = 0.f;
    }
}

// ---------------------------------------------------------------------------
extern "C" void kernel_launch(void* const* d_in, const int* in_sizes, int n_in,
                              void* d_out, int out_size, void* d_ws, size_t ws_size,
                              hipStream_t stream) {
    const float* points = (const float*)d_in[0];
    const float* gt     = (const float*)d_in[1];
    const float* logits = (const float*)d_in[2];
    const float* reg    = (const float*)d_in[3];
    float* out = (float*)d_out;

    u32* keys      = (u32*)((char*)d_ws + WS_KEYS);
    u64* cand      = (u64*)((char*)d_ws + WS_CAND);
    u64* tieb      = (u64*)((char*)d_ws + WS_TIEB);
    u32* cnts      = (u32*)((char*)d_ws + WS_CNT);
    float* sboxes  = (float*)((char*)d_ws + WS_SBOX);
    float* sscores = (float*)((char*)d_ws + WS_SSC);
    u64* mask   = (u64*)((char*)d_ws + WS_MASK);
    u64* diag   = (u64*)((char*)d_ws + WS_DIAG);
    u32* ghist  = (u32*)((char*)d_ws + WS_HIST);   // aliases head of mask

    hipMemsetAsync(cnts, 0, 16 * sizeof(u32), stream);   // cnt[8], tcnt[8]

    match_hist_kernel<<<30 * BATCH, 1024, 0, stream>>>(points, gt, logits,
                                                       out + OUT_MATCH, keys, ghist);

    select_kernel<<<BATCH, 1024, 0, stream>>>(ghist);

    compact_kernel<<<8 * BATCH, 1024, 0, stream>>>(keys, ghist, cand, tieb, cnts);

    sort_kernel<<<BATCH, SORT_T, 0, stream>>>(cand, tieb, cnts, ghist, reg, points,
                                              sboxes, sscores);

    mask_kernel<<<110 * BATCH, 256, 0, stream>>>(sboxes, sscores, mask, diag);

    scan_kernel<<<BATCH, 1024, 0, stream>>>(sboxes, sscores, mask, diag, out);
}

// Round 10
// 227.537 us; speedup vs baseline: 1.2447x; 1.2447x over previous
//
#include <hip/hip_runtime.h>
#include <stdint.h>

// Problem constants
#define N_POINTS   34100
#define BATCH      8
#define N_GT       200
#define NLEV       5
#define NCAND      3500
#define MAX_DET    300
#define SCORE_TH   0.05f
#define NMS_TH     0.5f
#define IMG        1280.0f
#define NBIN       4096
#define TIE_CAP    4096
// Exact threshold: RN(inter/denom) > 0.5  <=>  inter > T, T=(0.5+2^-25)*denom
// f32 fast path + f64 boundary fallback (R11-verified, absmax 0).
#define MTH 0.50000002980232238769531250

// Output layout (float32 flat, reference return order)
#define OUT_MATCH  0        // 8*34100
#define OUT_BOXES  272800   // 8*300*4
#define OUT_SCORES 282400   // 8*300
#define OUT_LABELS 284800   // 8*300
#define OUT_VALID  287200   // 8*300

// Workspace layout (bytes)
#define WS_KEYS    0              // u32[8*34100]   = 1,091,200
#define WS_SBOX    2632192        // float4[8*3500] =   448,000
#define WS_SSC     3080192        // float[8*3500]  =   112,000
#define WS_MASK    3192192        // u64[8*98560]   = 6,307,840
#define WS_DIAG    9500032        // u64[8*3520]    =   225,280
// Per-chunk partial level-histograms, ALIASED onto head of WS_MASK
// (stream-ordered liveness: consumed before mask_kernel rewrites).
#define WS_HIST    WS_MASK        // u32[8][5][8][4096] = 5,242,880
#define HSUB       8
#define MASK_STRIDE 98560
#define DIAG_STRIDE 3520

// R22: BEST-OF RECONSTRUCTION at minimum launch count (4).
// R21 post-mortem: every 8-block stage measures ~2.5x its work model
// (launch-gap/DVFS floor); splitting stages ADDS floors (R21: 283us).
// Fused pipeline (57us) < split select+compact+sort (8+62.6+41). So:
//   match_hist (R20 fusion) -> pipeline (R18/R19 fused A'..E) ->
//   mask (R13/R16) -> scan (R20 warming + R19 store-free picks).
// All components individually harness-verified (absmax 0).

typedef unsigned long long u64;
typedef uint32_t u32;

// Packed upper-triangle row offset: row c stores words (c>>6)..54
__device__ __forceinline__ int mask_off(int c) {
    int g = c >> 6;
    return 64 * (55 * g - (g * (g - 1)) / 2) + (c - (g << 6)) * (55 - g);
}

__device__ __forceinline__ int level_of(int p) {
    return (p < 25600) ? 0 : (p < 32000) ? 1 : (p < 33600) ? 2 : (p < 34000) ? 3 : 4;
}
__device__ __forceinline__ int loff_of(int l) {
    return (l == 0) ? 0 : (l == 1) ? 25600 : (l == 2) ? 32000 : (l == 3) ? 33600 : 34000;
}
__device__ __forceinline__ int k_of(int l) {
    return (l == 0) ? 1000 : (l == 1) ? 1000 : (l == 2) ? 1000 : (l == 3) ? 400 : 100;
}
__device__ __forceinline__ u64 readlane64(u64 v, int t) {
    u32 lo = (u32)__builtin_amdgcn_readlane((int)(u32)v, t);
    u32 hi = (u32)__builtin_amdgcn_readlane((int)(u32)(v >> 32), t);
    return ((u64)hi << 32) | lo;
}

// ---------------------------------------------------------------------------
// Kernel 1 (R20): fused match + hist. Grid 240: g = bid>>3, batch = bid&7.
// ---------------------------------------------------------------------------
__global__ __launch_bounds__(1024)
void match_hist_kernel(const float* __restrict__ points,
                       const float* __restrict__ gt,
                       const float* __restrict__ logits,
                       float* __restrict__ out_match,
                       u32* __restrict__ keys,
                       u32* __restrict__ ghist) {
#pragma clang fp contract(off)
    __shared__ float bx1[N_GT], by1[N_GT], bx2[N_GT], by2[N_GT], ar[N_GT];
    __shared__ u32 hh[NBIN];
    const int b = blockIdx.x & 7;
    const int g = blockIdx.x >> 3;           // 0..29
    const int tid = threadIdx.x;

    if (g < 17) {
        // ---- match part: points [g*2048, g*2048+2048) ----
        const int base = g * 2048 + tid;
        for (int j = tid; j < N_GT; j += 1024) {
            float x1 = gt[(b * N_GT + j) * 4 + 0];
            float y1 = gt[(b * N_GT + j) * 4 + 1];
            float x2 = gt[(b * N_GT + j) * 4 + 2];
            float y2 = gt[(b * N_GT + j) * 4 + 3];
            bx1[j] = x1; by1[j] = y1; bx2[j] = x2; by2[j] = y2;
            ar[j] = (x2 - x1) * (y2 - y1);
        }
        __syncthreads();

        const float BIGF = 2147483648.0f;   // float32(2^31-1) rounds to 2^31
        float px[2], py[2], best[2];
        int bi[2];
#pragma unroll
        for (int k = 0; k < 2; ++k) {
            int p = base + k * 1024;
            int pc = (p < N_POINTS) ? p : 0;
            px[k] = points[pc * 2 + 0];
            py[k] = points[pc * 2 + 1];
            best[k] = BIGF; bi[k] = -1;
        }
        for (int j = 0; j < N_GT; ++j) {
            float x1 = bx1[j], y1 = by1[j], x2 = bx2[j], y2 = by2[j], a = ar[j];
#pragma unroll
            for (int k = 0; k < 2; ++k) {
                bool inside = (px[k] >= x1) && (px[k] <= x2) &&
                              (py[k] >= y1) && (py[k] <= y2);
                float cost = inside ? a : BIGF;
                if (cost < best[k]) { best[k] = cost; bi[k] = j; }   // strict <
            }
        }
#pragma unroll
        for (int k = 0; k < 2; ++k) {
            int p = base + k * 1024;
            if (p >= N_POINTS) continue;
            out_match[b * N_POINTS + p] = (float)bi[k];
        }
    } else {
        // ---- hist part: sigmoid keys + partial level histogram ----
        const int f = g - 17;                // 0..12
        int lev, sub, p0, cnt;
        if (f < 8)       { lev = 0; sub = f;     p0 = f * 3200;               cnt = 3200; }
        else if (f < 10) { lev = 1; sub = f - 8; p0 = 25600 + (f - 8) * 3200; cnt = 3200; }
        else if (f == 10){ lev = 2; sub = 0;     p0 = 32000;                  cnt = 1600; }
        else if (f == 11){ lev = 3; sub = 0;     p0 = 33600;                  cnt = 400;  }
        else             { lev = 4; sub = 0;     p0 = 34000;                  cnt = 100;  }

        for (int i = tid; i < NBIN; i += 1024) hh[i] = 0u;
        __syncthreads();

        for (int i = tid; i < cnt; i += 1024) {
            int p = p0 + i;
            float lg = logits[b * N_POINTS + p];
            float s = 1.0f / (1.0f + expf(-lg));
            u32 u = __float_as_uint(s);
            u32 key = (u & 0x80000000u) ? ~u : (u | 0x80000000u);
            keys[b * N_POINTS + p] = key;
            atomicAdd(&hh[(key >> 19) & 4095u], 1u);
        }
        __syncthreads();

        u32* outp = ghist + (((u32)b * NLEV + (u32)lev) * HSUB + (u32)sub) * NBIN;
        for (int i = tid; i < NBIN; i += 1024) outp[i] = hh[i];
    }
}

// ---------------------------------------------------------------------------
// Kernel 2: fused pipeline (R18/R19):
//   A': coalesced ghist load+sum -> swizzled LDS; keys L2 warm (4-deep MLP)
//   B: 5 threshold selects in PARALLEL (waves 0..4), LDS-only reads
//   C: one compact pass, 4-way key prefetch (keys L2-warm)
//   D: tie-select, append to sk
//   E: counting sort + exact intra-digit rank + decode
// ---------------------------------------------------------------------------
#define SORT_T 1024
// Swizzled LDS histogram: bin j of level lev at lsb[lev*4160 + (j&63)*65 + (j>>6)]
#define LSWZ(j) (((j) & 63) * 65 + ((j) >> 6))
__global__ __launch_bounds__(SORT_T)
void pipeline_kernel(const u32* __restrict__ keys,
                     const u32* __restrict__ ghist,
                     const float* __restrict__ reg,
                     const float* __restrict__ points,
                     float* __restrict__ sboxes,
                     float* __restrict__ sscores) {
#pragma clang fp contract(off)
    __shared__ __align__(16) char smem[131072];
    u64* sk   = (u64*)smem;                  //     0..32768 : 4096 u64 (C..E)
    u64* tb   = (u64*)(smem + 32768);        // 32768..65536 : 4096 u64 (C/D)
    u64* aux  = (u64*)(smem + 65536);        // 65536..98304 : 4096 u64 (E)
    u32* h    = (u32*)(smem + 98304);        // 98304..114688: 4096 u32 (E)
    u32* bs   = (u32*)(smem + 114688);       // 114688..131072: 4096 u32 (E)
    u32* lsb  = (u32*)smem;                  // A'/B only: [5][4160] u32 = 83,200B
    __shared__ u32 sTl[NLEV], skkl[NLEV], wt[16];
    __shared__ u32 scnt, stcnt;

    const int b = blockIdx.x;
    const int tid = threadIdx.x;
    const int lane = tid & 63;
    const int wid = tid >> 6;
    const u32* kk_ = keys + b * N_POINTS;

    if (tid == 0) { scnt = 0u; stcnt = 0u; }

    // ---- Phase A': coalesced partial-hist sum -> swizzled LDS + keys warm --
    {
        const u32* hb = ghist + (u32)b * (NLEV * HSUB * NBIN);
#pragma unroll
        for (int lev = 0; lev < NLEV; ++lev) {
            const int SUBS = (lev == 0) ? 8 : (lev == 1) ? 2 : 1;
            const u32* hl = hb + lev * HSUB * NBIN + tid;
            u32 s0 = 0, s1 = 0, s2 = 0, s3 = 0;
#pragma unroll
            for (int sub = 0; sub < SUBS; ++sub) {
                const u32* hs = hl + sub * NBIN;
                s0 += hs[0]; s1 += hs[1024]; s2 += hs[2048]; s3 += hs[3072];
            }
            u32* lv = lsb + lev * 4160;
            lv[LSWZ(tid)]        = s0;
            lv[LSWZ(tid + 1024)] = s1;
            lv[LSWZ(tid + 2048)] = s2;
            lv[LSWZ(tid + 3072)] = s3;
        }
        // keys slab warm (8525 uint4 exactly), 4 independent accumulators
        const uint4* kp4 = (const uint4*)kk_;
        u32 a0 = 0, a1 = 0, a2 = 0, a3 = 0;
        int i = tid;
        for (; i + 3072 < 8525; i += 4096) {
            uint4 v0 = kp4[i];
            uint4 v1 = kp4[i + 1024];
            uint4 v2 = kp4[i + 2048];
            uint4 v3 = kp4[i + 3072];
            a0 ^= v0.x ^ v0.y ^ v0.z ^ v0.w;
            a1 ^= v1.x ^ v1.y ^ v1.z ^ v1.w;
            a2 ^= v2.x ^ v2.y ^ v2.z ^ v2.w;
            a3 ^= v3.x ^ v3.y ^ v3.z ^ v3.w;
        }
        for (; i < 8525; i += 1024) {
            uint4 v = kp4[i];
            a0 ^= v.x ^ v.y ^ v.z ^ v.w;
        }
        u32 wacc = a0 ^ a1 ^ a2 ^ a3;
        asm volatile("" :: "v"(wacc));       // keep warming loads live
    }
    __syncthreads();

    // ---- Phase B: 5 parallel selects (wave w handles level w), LDS-only ----
    if (wid < NLEV) {
        const u32 K = (u32)k_of(wid);
        const u32* hh = lsb + wid * 4160;    // swizzled summed histogram
        u32 S = 0;
#pragma unroll 16
        for (int i = 0; i < 64; ++i) S += hh[i * 65 + lane];   // bins lane*64+i
        u32 acc = S;
#pragma unroll
        for (int off = 1; off < 64; off <<= 1) {
            u32 v = (u32)__shfl_down((int)acc, off);
            if (lane + off < 64) acc += v;
        }
        u32 sfxAfter = acc - S;
        bool hit = (sfxAfter < K) && (sfxAfter + S >= K);
        u64 bal = __ballot(hit);
        int Lg = (int)__builtin_ctzll(bal);
        u32 sfxG = (u32)__shfl((int)sfxAfter, Lg);

        u32 v = hh[lane * 65 + Lg];          // bin Lg*64+lane
        u32 acc2 = v;
#pragma unroll
        for (int off = 1; off < 64; off <<= 1) {
            u32 t = (u32)__shfl_down((int)acc2, off);
            if (lane + off < 64) acc2 += t;
        }
        u32 sfx2 = sfxG + acc2 - v;
        bool hit2 = (sfx2 < K) && (sfx2 + v >= K);
        if (hit2) { sTl[wid] = (u32)(Lg * 64 + lane); skkl[wid] = K - sfx2; }
    }
    __syncthreads();                         // lsb dead after this point

    // ---- Phase C: one compact pass over all points (4-way prefetched) ----
    const u64 below = (lane == 0) ? 0ull : (~0ull >> (64 - lane));
    const int CHUNK = 4 * SORT_T;
    for (int it = 0; it < (N_POINTS + CHUNK - 1) / CHUNK; ++it) {
        u32 key4[4]; int pc4[4]; bool act4[4];
#pragma unroll
        for (int u = 0; u < 4; ++u) {
            int i = it * CHUNK + u * SORT_T + tid;
            act4[u] = (i < N_POINTS);
            pc4[u] = act4[u] ? i : (N_POINTS - 1);
            key4[u] = kk_[pc4[u]];
        }
#pragma unroll
        for (int u = 0; u < 4; ++u) {
            bool active = act4[u];
            int pc = pc4[u];
            u32 key = key4[u];
            int l = level_of(pc);
            u32 digit = (key >> 19) & 4095u;
            u32 T = sTl[l];
            bool isDef = active && (digit > T);
            bool isTie = active && (digit == T);
            u64 k50 = ((u64)key << 18) | ((u64)(7 - l) << 15)
                    | (u64)(32767 - (pc - loff_of(l)));
            u64 grp = __ballot(isDef);
            if (grp) {
                int leader = (int)__builtin_ctzll(grp);
                u32 base_ = 0;
                if (lane == leader)
                    base_ = atomicAdd(&scnt, (u32)__builtin_popcountll(grp));
                base_ = (u32)__shfl((int)base_, leader);
                if (isDef) sk[base_ + (u32)__builtin_popcountll(grp & below)] = k50;
            }
            u64 tg = __ballot(isTie);
            if (tg) {
                int leader = (int)__builtin_ctzll(tg);
                u32 base_ = 0;
                if (lane == leader)
                    base_ = atomicAdd(&stcnt, (u32)__builtin_popcountll(tg));
                base_ = (u32)__shfl((int)base_, leader);
                if (isTie) {
                    u32 pos = base_ + (u32)__builtin_popcountll(tg & below);
                    if (pos < TIE_CAP) tb[pos] = k50;
                }
            }
        }
    }
    __syncthreads();

    // ---- Phase D: tie-select (rank among same-level ties), append to sk ----
    int t = (int)stcnt; if (t > TIE_CAP) t = TIE_CAP;
    for (int j0 = tid; j0 - tid < t; j0 += SORT_T) {
        bool active = j0 < t;
        u64 kj = active ? tb[j0] : 0ull;
        u32 lvtag = (u32)(kj >> 15) & 7u;
        int r = 0;
        for (int i = 0; i < t; ++i) {
            u64 ki = tb[i];                   // broadcast read
            r += (ki > kj && (((u32)(ki >> 15) & 7u) == lvtag)) ? 1 : 0;
        }
        bool inc = active && (r < (int)skkl[7 - lvtag]);
        u64 grp = __ballot(inc);
        if (grp) {
            int leader = (int)__builtin_ctzll(grp);
            u32 base_ = 0;
            if (lane == leader)
                base_ = atomicAdd(&scnt, (u32)__builtin_popcountll(grp));
            base_ = (u32)__shfl((int)base_, leader);
            if (inc) sk[base_ + (u32)__builtin_popcountll(grp & below)] = kj;
        }
    }
    __syncthreads();
    const int total = (int)scnt;             // == 3500 by construction

    // ---- Phase E: counting sort by digit (desc) + exact intra-digit rank ----
    for (int i = tid; i < NBIN; i += SORT_T) h[i] = 0u;
    __syncthreads();
    for (int i = tid; i < total; i += SORT_T)
        atomicAdd(&h[(u32)(sk[i] >> 37) & 4095u], 1u);
    __syncthreads();

    u32 t0 = h[4095 - 4 * tid];
    u32 t1 = h[4095 - (4 * tid + 1)];
    u32 t2 = h[4095 - (4 * tid + 2)];
    u32 t3 = h[4095 - (4 * tid + 3)];
    u32 tsum = t0 + t1 + t2 + t3;
    u32 sc_ = tsum;
#pragma unroll
    for (int off = 1; off < 64; off <<= 1) {
        u32 v = (u32)__shfl_up((int)sc_, off);
        if (lane >= off) sc_ += v;
    }
    if (lane == 63) wt[wid] = sc_;
    __syncthreads();
    if (tid < 64) {
        u32 v = (tid < 16) ? wt[tid] : 0u;
        u32 s2 = v;
#pragma unroll
        for (int off = 1; off < 16; off <<= 1) {
            u32 x = (u32)__shfl_up((int)s2, off);
            if (tid >= off) s2 += x;
        }
        if (tid < 16) wt[tid] = s2 - v;      // exclusive wave offsets
    }
    __syncthreads();
    u32 run = (sc_ - tsum) + wt[wid];
    bs[4095 - 4 * tid] = run;       run += t0;
    bs[4095 - (4 * tid + 1)] = run; run += t1;
    bs[4095 - (4 * tid + 2)] = run; run += t2;
    bs[4095 - (4 * tid + 3)] = run;
    __syncthreads();
    for (int i = tid; i < NBIN; i += SORT_T) h[i] = 0u;
    __syncthreads();
    for (int i = tid; i < total; i += SORT_T) {
        u64 k = sk[i];
        u32 d = (u32)(k >> 37) & 4095u;
        u32 pos = bs[d] + atomicAdd(&h[d], 1u);
        aux[pos] = k;
    }
    __syncthreads();
    for (int p = tid; p < total; p += SORT_T) {
        u64 kp = aux[p];
        u32 d = (u32)(kp >> 37) & 4095u;
        u32 gbase = bs[d];
        u32 gend = (d == 0) ? (u32)total : bs[d - 1];
        u32 r = 0;
        for (u32 q = gbase; q < gend; ++q) r += (aux[q] > kp) ? 1u : 0u;
        sk[gbase + r] = kp;                  // unique keys -> exact slot
    }
    __syncthreads();

    // decode + write sorted candidates
    for (int r = tid; r < NCAND; r += SORT_T) {
        float x1 = 0.f, y1 = 0.f, x2 = 0.f, y2 = 0.f, sc = 0.f;
        if (r < total) {
            u64 k50 = sk[r];
            int lowb = (int)(k50 & 0x3FFFFull);
            int l = 7 - (lowb >> 15);
            int idxl = 32767 - (lowb & 32767);
            int p = loff_of(l) + idxl;
            u32 key32 = (u32)(k50 >> 18);
            sc = __uint_as_float(key32 ^ 0x80000000u);
            int gp = b * N_POINTS + p;
            float l_ = reg[gp * 4 + 0] * IMG;
            float t_ = reg[gp * 4 + 1] * IMG;
            float r_ = reg[gp * 4 + 2] * IMG;
            float bb = reg[gp * 4 + 3] * IMG;
            float px = points[p * 2 + 0];
            float py = points[p * 2 + 1];
            x1 = fminf(fmaxf(px - l_, 0.0f), IMG);
            y1 = fminf(fmaxf(py - t_, 0.0f), IMG);
            x2 = fminf(fmaxf(px + r_, 0.0f), IMG);
            y2 = fminf(fmaxf(py + bb, 0.0f), IMG);
        }
        int slot = b * NCAND + r;
        sboxes[slot * 4 + 0] = x1;
        sboxes[slot * 4 + 1] = y1;
        sboxes[slot * 4 + 2] = x2;
        sboxes[slot * 4 + 3] = y2;
        sscores[slot] = sc;
    }
}

// ---------------------------------------------------------------------------
// Kernel 3: suppression-mask matrix (R13 load-balanced mirror pairs).
// R16: 1D grid of 880, batch = bid&7.
// ---------------------------------------------------------------------------
__global__ __launch_bounds__(256)
void mask_kernel(const float* __restrict__ sboxes,
                 const float* __restrict__ sscores,
                 u64* __restrict__ mask,
                 u64* __restrict__ diag) {
#pragma clang fp contract(off)
    const int b = blockIdx.x & 7;                // XCD-local batch
    const int gx = blockIdx.x >> 3;              // 0..109
    const int wv = threadIdx.x >> 6;
    const int lane = threadIdx.x & 63;
    const int NG = (NCAND + 3) >> 2;             // 875 row-groups
    const int NH = (NG + 1) >> 1;                // 438 balanced pairs
    const int gidx = gx * 4 + wv;
    if (gidx >= NH) return;

    const float4* gb = (const float4*)sboxes + b * NCAND;
    const float* gs = sscores + b * NCAND;
    u64* mout = mask + (size_t)b * MASK_STRIDE;
    u64* dout = diag + (size_t)b * DIAG_STRIDE;

    for (int s = 0; s < 2; ++s) {
        const int g0 = (s == 0) ? gidx : (NG - 1 - gidx);
        if (s == 1 && g0 == gidx) break;         // odd middle processed once
        const int c0 = g0 << 2;

        float4 bc[4]; float a1[4]; bool ok[4]; int g[4]; u64* rp[4];
        bool any = false;
#pragma unroll
        for (int i = 0; i < 4; ++i) {
            int c = c0 + i;
            int cc = (c < NCAND) ? c : (NCAND - 1);
            bc[i] = gb[cc];
            a1[i] = (bc[i].z - bc[i].x) * (bc[i].w - bc[i].y);
            ok[i] = (c < NCAND) && (gs[cc] > SCORE_TH);
            g[i] = cc >> 6;
            rp[i] = mout + mask_off(cc) - g[i];
            any |= ok[i];
        }
        if (!any) continue;                      // wave-uniform

        for (int w = (c0 >> 6); w < 55; ++w) {
            int cj = (w << 6) + lane;
            float4 bj = (cj < NCAND) ? gb[cj] : make_float4(0.f, 0.f, 0.f, 0.f);
            float a2 = (bj.z - bj.x) * (bj.w - bj.y);
#pragma unroll
            for (int i = 0; i < 4; ++i) {
                float x1 = fmaxf(bc[i].x, bj.x);
                float y1 = fmaxf(bc[i].y, bj.y);
                float x2 = fminf(bc[i].z, bj.z);
                float y2 = fminf(bc[i].w, bj.w);
                float inter = fmaxf(x2 - x1, 0.f) * fmaxf(y2 - y1, 0.f);
                float denom = a1[i] + a2 - inter + 1e-9f;   // ref association
                float hf = 0.5f * denom;                    // exact
                float rr = fmaf(0x1p-25f, denom, hf);       // RN(T)
                u64 bits = __ballot(inter > rr);
                u64 eq = __ballot(inter == rr);
                if (eq) {                                   // boundary: exact f64
                    u64 fb = __ballot((double)inter > MTH * (double)denom);
                    bits |= (eq & fb);
                }
                if (lane == 0 && ok[i] && w >= g[i]) {
                    rp[i][w] = bits;
                    if (w == g[i]) dout[c0 + i] = bits;     // dense diagonal
                }
            }
        }
    }
}

// ---------------------------------------------------------------------------
// Kernel 4: sorted-order NMS scan (R20 form: 8-deep warm MLP + sboxes/
// sscores warm; store-free pick loop with LDS pick list).
// ---------------------------------------------------------------------------
__global__ __launch_bounds__(1024)
void scan_kernel(const float* __restrict__ sboxes,
                 const float* __restrict__ sscores,
                 const u64* __restrict__ mask,
                 const u64* __restrict__ diag,
                 float* __restrict__ out) {
    __shared__ u32 pick_idx[MAX_DET];
    const int b = blockIdx.x;
    const int tid = threadIdx.x;
    const u64* mrow = mask + (size_t)b * MASK_STRIDE;
    const u64* drow = diag + (size_t)b * DIAG_STRIDE;
    const float4* gb = (const float4*)sboxes + b * NCAND;
    const float* gs = sscores + b * NCAND;

    if (tid >= 64) {
        // ---- L2-warming waves: mask (8-deep) + diag + sboxes + sscores ----
        const uint4* mp = (const uint4*)mrow;          // 49280 uint4
        const uint4* dp = (const uint4*)drow;          // 1760 uint4
        const uint4* bp = (const uint4*)gb;            // 3500 uint4
        const uint4* sp = (const uint4*)gs;            // 875 uint4
        const int t = tid - 64;                        // 0..959
        u32 a0 = 0, a1 = 0, a2 = 0, a3 = 0, a4 = 0, a5 = 0, a6 = 0, a7 = 0;
        int i = t;
        for (; i + 6720 < 49280; i += 7680) {          // 8 loads in flight
            uint4 v0 = mp[i];
            uint4 v1 = mp[i + 960];
            uint4 v2 = mp[i + 1920];
            uint4 v3 = mp[i + 2880];
            uint4 v4 = mp[i + 3840];
            uint4 v5 = mp[i + 4800];
            uint4 v6 = mp[i + 5760];
            uint4 v7 = mp[i + 6720];
            a0 ^= v0.x ^ v0.y ^ v0.z ^ v0.w;
            a1 ^= v1.x ^ v1.y ^ v1.z ^ v1.w;
            a2 ^= v2.x ^ v2.y ^ v2.z ^ v2.w;
            a3 ^= v3.x ^ v3.y ^ v3.z ^ v3.w;
            a4 ^= v4.x ^ v4.y ^ v4.z ^ v4.w;
            a5 ^= v5.x ^ v5.y ^ v5.z ^ v5.w;
            a6 ^= v6.x ^ v6.y ^ v6.z ^ v6.w;
            a7 ^= v7.x ^ v7.y ^ v7.z ^ v7.w;
        }
        for (; i < 49280; i += 960) {
            uint4 v = mp[i];
            a0 ^= v.x ^ v.y ^ v.z ^ v.w;
        }
        if (t < 880) {                                 // diag: 2 per thread
            uint4 v0 = dp[t];
            uint4 v1 = dp[t + 880];
            a1 ^= v0.x ^ v0.y ^ v0.z ^ v0.w;
            a2 ^= v1.x ^ v1.y ^ v1.z ^ v1.w;
        }
        for (int j = t; j < 3500; j += 960) {          // sboxes
            uint4 v = bp[j];
            a3 ^= v.x ^ v.y ^ v.z ^ v.w;
        }
        if (t < 875) {                                 // sscores
            uint4 v = sp[t];
            a4 ^= v.x ^ v.y ^ v.z ^ v.w;
        }
        u32 acc = (a0 ^ a1) ^ (a2 ^ a3) ^ (a4 ^ a5) ^ (a6 ^ a7);
        asm volatile("" :: "v"(acc));                  // keep loads live
        return;
    }

    const int lane = tid;                    // 64 threads = 1 wave

    float* ob = out + OUT_BOXES  + b * MAX_DET * 4;
    float* os = out + OUT_SCORES + b * MAX_DET;
    float* ol = out + OUT_LABELS + b * MAX_DET;
    float* ov = out + OUT_VALID  + b * MAX_DET;

    u64 m = 0ull;                            // lane f owns future-word f
    u64 rowN = drow[lane];                   // contiguous diagonal prefetch
    float sjN = gs[lane];

    int kept = 0;
    for (int w = 0; w < 55; ++w) {
        const int wbase = w << 6;
        const u64 row = rowN;
        const float sj = sjN;
        if (w < 54) {                        // prefetch next word (contiguous)
            int cn = wbase + 64 + lane;
            int cc = (cn < NCAND) ? cn : (NCAND - 1);
            rowN = drow[cc];
            float s = gs[cc];
            sjN = (cn < NCAND) ? s : 0.f;
        }
        int c = wbase + lane;
        u64 bad = __ballot(!((c < NCAND) && (sj > SCORE_TH)));
        u64 cur = readlane64(m, w) | bad;
        u64 km = 0ull;
        while (kept < MAX_DET) {
            u64 avail = ~cur;
            if (avail == 0ull) break;
            int t = (int)__builtin_ctzll(avail);       // uniform
            u64 r = readlane64(row, t);                // keep t's intra bits
            cur |= r | (1ull << t);
            km |= 1ull << t;
            if (lane == 0) pick_idx[kept] = (u32)(wbase + t);  // LDS, off vmem path
            kept++;
        }
        if (km) {
            const bool lr = (lane >= w && lane < 55);
            const int lo = lane - w;
            u64 acc = 0ull;
            while (km) {
#define POPBIT(tn) int tn = -1; if (km) { tn = (int)__builtin_ctzll(km); km &= km - 1ull; }
                POPBIT(t0) POPBIT(t1) POPBIT(t2) POPBIT(t3)
                POPBIT(t4) POPBIT(t5) POPBIT(t6) POPBIT(t7)
#undef POPBIT
                u64 v0 = 0, v1 = 0, v2 = 0, v3 = 0, v4 = 0, v5 = 0, v6 = 0, v7 = 0;
                if (lr) {
                    v0 = mrow[mask_off(wbase + t0) + lo];
                    if (t1 >= 0) v1 = mrow[mask_off(wbase + t1) + lo];
                    if (t2 >= 0) v2 = mrow[mask_off(wbase + t2) + lo];
                    if (t3 >= 0) v3 = mrow[mask_off(wbase + t3) + lo];
                    if (t4 >= 0) v4 = mrow[mask_off(wbase + t4) + lo];
                    if (t5 >= 0) v5 = mrow[mask_off(wbase + t5) + lo];
                    if (t6 >= 0) v6 = mrow[mask_off(wbase + t6) + lo];
                    if (t7 >= 0) v7 = mrow[mask_off(wbase + t7) + lo];
                }
                acc |= ((v0 | v1) | (v2 | v3)) | ((v4 | v5) | (v6 | v7));
            }
            m |= acc;
        }
        if (kept >= MAX_DET) break;
    }

    // ---- coalesced epilogue: gather picked candidates, write outputs ----
    for (int k = lane; k < kept; k += 64) {
        u32 c = pick_idx[k];                 // same-wave LDS, no barrier needed
        float4 bx = gb[c];
        float s = gs[c];
        ob[k * 4 + 0] = bx.x;
        ob[k * 4 + 1] = bx.y;
        ob[k * 4 + 2] = bx.z;
        ob[k * 4 + 3] = bx.w;
        os[k] = s;
        ol[k] = 0.0f;
        ov[k] = 1.0f;
    }
    for (int k = kept + lane; k < MAX_DET; k += 64) {
        ob[k * 4 + 0] = 0.f; ob[k * 4 + 1] = 0.f;
        ob[k * 4 + 2] = 0.f; ob[k * 4 + 3] = 0.f;
        os[k] = 0.f; ol[k] = -1.f; ov[k] = 0.f;
    }
}

// ---------------------------------------------------------------------------
extern "C" void kernel_launch(void* const* d_in, const int* in_sizes, int n_in,
                              void* d_out, int out_size, void* d_ws, size_t ws_size,
                              hipStream_t stream) {
    const float* points = (const float*)d_in[0];
    const float* gt     = (const float*)d_in[1];
    const float* logits = (const float*)d_in[2];
    const float* reg    = (const float*)d_in[3];
    float* out = (float*)d_out;

    u32* keys      = (u32*)((char*)d_ws + WS_KEYS);
    float* sboxes  = (float*)((char*)d_ws + WS_SBOX);
    float* sscores = (float*)((char*)d_ws + WS_SSC);
    u64* mask   = (u64*)((char*)d_ws + WS_MASK);
    u64* diag   = (u64*)((char*)d_ws + WS_DIAG);
    u32* ghist  = (u32*)((char*)d_ws + WS_HIST);   // aliases head of mask

    match_hist_kernel<<<30 * BATCH, 1024, 0, stream>>>(points, gt, logits,
                                                       out + OUT_MATCH, keys, ghist);

    pipeline_kernel<<<BATCH, SORT_T, 0, stream>>>(keys, ghist, reg, points,
                                                  sboxes, sscores);

    mask_kernel<<<110 * BATCH, 256, 0, stream>>>(sboxes, sscores, mask, diag);

    scan_kernel<<<BATCH, 1024, 0, stream>>>(sboxes, sscores, mask, diag, out);
}